// Round 4
// baseline (258.658 us; speedup 1.0000x reference)
//
#include <hip/hip_runtime.h>
#include <math.h>

// Fused 3-layer MLP: h1 = relu(x@W1^T+b1) [B,3]; h2 = relu(h1@W2^T+b2) [B,2];
// out = sigmoid(h2@W3^T+b3) [B].  All fp32.  Memory-bound: 32 B/row traffic
// (8 B read + 24 B write) = 256 MiB at B=8.39M -> ~41 us floor @6.6 TB/s.
//
// Structure: block owns RPB=1024 rows; compute into LDS; drain with fully
// lane-contiguous float4 non-temporal stores (no RFO, full-line coverage).
// R4: thread computes 4 CONSECUTIVE rows so every LDS write is an aligned
// ds_write_b128 (6 per thread vs ~12 scalar b32 in R3). Headline dur_us
// includes ~170-190 us of harness poison-fill work (768 MiB d_ws fill etc.,
// visible in rocprof); kernel itself is <120 us and near the 41 us floor.

#define RPB 1024  // rows per block (256 threads x 4 rows)

typedef float v4f __attribute__((ext_vector_type(4)));

__global__ __launch_bounds__(256) void mlp321_kernel(
    const float* __restrict__ x,
    const float* __restrict__ W1, const float* __restrict__ b1,
    const float* __restrict__ W2, const float* __restrict__ b2,
    const float* __restrict__ W3, const float* __restrict__ b3,
    float* __restrict__ out_p, float* __restrict__ h1_p, float* __restrict__ h2_p,
    int nrows)
{
    __shared__ __align__(16) float s_h1[RPB * 3];  // 12 KB
    __shared__ __align__(16) float s_h2[RPB * 2];  //  8 KB
    __shared__ __align__(16) float s_out[RPB];     //  4 KB

    const int tid = threadIdx.x;
    const size_t base = (size_t)blockIdx.x * RPB;

    // Weights: tiny, uniform -> scalar loads / cache broadcast.
    float w1[6], w2[6], w3v[2], bb1[3], bb2[2], bb3;
#pragma unroll
    for (int i = 0; i < 6; ++i) w1[i] = W1[i];
#pragma unroll
    for (int i = 0; i < 3; ++i) bb1[i] = b1[i];
#pragma unroll
    for (int i = 0; i < 6; ++i) w2[i] = W2[i];
#pragma unroll
    for (int i = 0; i < 2; ++i) bb2[i] = b2[i];
    w3v[0] = W3[0]; w3v[1] = W3[1];
    bb3 = b3[0];

    const bool full = (base + RPB) <= (size_t)nrows;

    if (full) {
        // ---- compute: 4 consecutive rows/thread, all-vector LDS writes ----
        const int r0 = tid * 4;  // rows [r0, r0+4) within block
        const v4f* xv = reinterpret_cast<const v4f*>(x + base * 2);
        v4f xa = xv[tid * 2 + 0];
        v4f xb = xv[tid * 2 + 1];
        float xr[4][2] = {{xa.x, xa.y}, {xa.z, xa.w}, {xb.x, xb.y}, {xb.z, xb.w}};

        float h1v[4][3], h2v[4][2], ov[4];
#pragma unroll
        for (int r = 0; r < 4; ++r) {
            const float x0 = xr[r][0], x1 = xr[r][1];
#pragma unroll
            for (int j = 0; j < 3; ++j) {
                float v = fmaf(x0, w1[j * 2 + 0], fmaf(x1, w1[j * 2 + 1], bb1[j]));
                h1v[r][j] = v > 0.f ? v : 0.f;
            }
#pragma unroll
            for (int k = 0; k < 2; ++k) {
                float v = bb2[k];
#pragma unroll
                for (int j = 0; j < 3; ++j) v = fmaf(h1v[r][j], w2[k * 3 + j], v);
                h2v[r][k] = v > 0.f ? v : 0.f;
            }
            float z = fmaf(h2v[r][0], w3v[0], fmaf(h2v[r][1], w3v[1], bb3));
            ov[r] = 1.f / (1.f + __expf(-z));
        }

        // LDS writes: all aligned b128.
        v4f* l1 = reinterpret_cast<v4f*>(s_h1 + r0 * 3);  // 3 v4f
        l1[0] = (v4f){h1v[0][0], h1v[0][1], h1v[0][2], h1v[1][0]};
        l1[1] = (v4f){h1v[1][1], h1v[1][2], h1v[2][0], h1v[2][1]};
        l1[2] = (v4f){h1v[2][2], h1v[3][0], h1v[3][1], h1v[3][2]};
        v4f* l2 = reinterpret_cast<v4f*>(s_h2 + r0 * 2);  // 2 v4f
        l2[0] = (v4f){h2v[0][0], h2v[0][1], h2v[1][0], h2v[1][1]};
        l2[1] = (v4f){h2v[2][0], h2v[2][1], h2v[3][0], h2v[3][1]};
        reinterpret_cast<v4f*>(s_out + r0)[0] = (v4f){ov[0], ov[1], ov[2], ov[3]};

        __syncthreads();

        // ---- drain: fully coalesced float4 non-temporal stores ----
        const v4f* so = reinterpret_cast<const v4f*>(s_out);
        const v4f* s1 = reinterpret_cast<const v4f*>(s_h1);
        const v4f* s2 = reinterpret_cast<const v4f*>(s_h2);
        v4f* po = reinterpret_cast<v4f*>(out_p + base);       // 256 v4f
        v4f* p1 = reinterpret_cast<v4f*>(h1_p + base * 3);    // 768 v4f
        v4f* p2 = reinterpret_cast<v4f*>(h2_p + base * 2);    // 512 v4f

        __builtin_nontemporal_store(so[tid], po + tid);
#pragma unroll
        for (int it = 0; it < 3; ++it) {
            const int i = it * 256 + tid;
            __builtin_nontemporal_store(s1[i], p1 + i);
        }
#pragma unroll
        for (int it = 0; it < 2; ++it) {
            const int i = it * 256 + tid;
            __builtin_nontemporal_store(s2[i], p2 + i);
        }
    } else {
        // tail block: scalar guarded path (not hit when B % RPB == 0)
        const int remain = (int)((size_t)nrows - base);
        for (int r = tid; r < remain; r += 256) {
            const float x0 = x[(base + r) * 2 + 0];
            const float x1 = x[(base + r) * 2 + 1];
            float h1v[3];
#pragma unroll
            for (int j = 0; j < 3; ++j) {
                float v = fmaf(x0, w1[j * 2 + 0], fmaf(x1, w1[j * 2 + 1], bb1[j]));
                h1v[j] = v > 0.f ? v : 0.f;
                h1_p[(base + r) * 3 + j] = h1v[j];
            }
            float h2v[2];
#pragma unroll
            for (int k = 0; k < 2; ++k) {
                float v = bb2[k];
#pragma unroll
                for (int j = 0; j < 3; ++j) v = fmaf(h1v[j], w2[k * 3 + j], v);
                h2v[k] = v > 0.f ? v : 0.f;
                h2_p[(base + r) * 2 + k] = h2v[k];
            }
            float z = fmaf(h2v[0], w3v[0], fmaf(h2v[1], w3v[1], bb3));
            out_p[base + r] = 1.f / (1.f + __expf(-z));
        }
    }
}

extern "C" void kernel_launch(void* const* d_in, const int* in_sizes, int n_in,
                              void* d_out, int out_size, void* d_ws, size_t ws_size,
                              hipStream_t stream) {
    const float* x  = (const float*)d_in[0];
    const float* W1 = (const float*)d_in[1];
    const float* b1 = (const float*)d_in[2];
    const float* W2 = (const float*)d_in[3];
    const float* b2 = (const float*)d_in[4];
    const float* W3 = (const float*)d_in[5];
    const float* b3 = (const float*)d_in[6];

    const int B = in_sizes[0] / 2;  // x is [B, 2]
    float* out_p = (float*)d_out;          // [B]
    float* h1_p  = out_p + (size_t)B;      // [B,3]
    float* h2_p  = h1_p + (size_t)B * 3;   // [B,2]

    const int blocks = (B + RPB - 1) / RPB;
    mlp321_kernel<<<blocks, 256, 0, stream>>>(x, W1, b1, W2, b2, W3, b3,
                                              out_p, h1_p, h2_p, B);
}